// Round 6
// baseline (4548.926 us; speedup 1.0000x reference)
//
#include <hip/hip_runtime.h>

#define BN 262144

typedef short bf16x8 __attribute__((ext_vector_type(8)));
typedef float f32x4 __attribute__((ext_vector_type(4)));

#define MFMA16(a,b,c) __builtin_amdgcn_mfma_f32_16x16x32_bf16((a),(b),(c),0,0,0)

__device__ __forceinline__ unsigned short f2bf(float f) {
  union { float f; unsigned int u; } x; x.f = f;
  unsigned int u = x.u + 0x7fffu + ((x.u >> 16) & 1u);
  return (unsigned short)(u >> 16);
}
__device__ __forceinline__ float bf2f(unsigned int h) {
  union { unsigned int u; float f; } x; x.u = h << 16;
  return x.f;
}

// All weight arrays in 16x16x32 B-fragment layout (ushort units):
// elem ((ct*KS+s)*64+lane)*8+j holds B[k][n], n = ct*16+(lane&15), k = s*32+(lane>>4)*8+j
#define O_R1 0        // W1^T: B[k][n]=W1[n*64+k]   K=64  N=256 KS=2
#define O_R2 16384    // W2^T: B[k][n]=W2[n*256+k]  K=256 N=256 KS=8
#define O_R3 81920    // W3^T: B[k][n]=W3[n*256+k]  K=256 N=64  KS=8
#define O_R4 98304    // W3  : B[k][n]=W3[k*256+n]  K=64  N=256 KS=2
#define O_R5 114688   // W2  : B[k][n]=W2[k*256+n]  K=256 N=256 KS=8
#define O_R6 180224   // W1  : B[k][n]=W1[k*64+n]   K=256 N=64  KS=8
#define N_WS 196608

__global__ void invres_prep(const float* __restrict__ W1, const float* __restrict__ W2,
                            const float* __restrict__ W3, unsigned short* __restrict__ wsb) {
  int idx = blockIdx.x * 256 + threadIdx.x;
  if (idx >= N_WS) return;
  int j = idx & 7;
  int lane = (idx >> 3) & 63;
  int nn = lane & 15, kn = (lane >> 4) * 8 + j;
  float val;
  if (idx < O_R2) {                // R1, KS=2
    int g = idx >> 9; int s = g & 1; int ct = g >> 1;
    val = W1[(ct * 16 + nn) * 64 + (s * 32 + kn)];
  } else if (idx < O_R3) {         // R2, KS=8
    int g = (idx - O_R2) >> 9; int s = g & 7; int ct = g >> 3;
    val = W2[(ct * 16 + nn) * 256 + (s * 32 + kn)];
  } else if (idx < O_R4) {         // R3, KS=8
    int g = (idx - O_R3) >> 9; int s = g & 7; int ct = g >> 3;
    val = W3[(ct * 16 + nn) * 256 + (s * 32 + kn)];
  } else if (idx < O_R5) {         // R4, KS=2
    int g = (idx - O_R4) >> 9; int s = g & 1; int ct = g >> 1;
    val = W3[(s * 32 + kn) * 256 + (ct * 16 + nn)];
  } else if (idx < O_R6) {         // R5, KS=8
    int g = (idx - O_R5) >> 9; int s = g & 7; int ct = g >> 3;
    val = W2[(s * 32 + kn) * 256 + (ct * 16 + nn)];
  } else {                         // R6, KS=8
    int g = (idx - O_R6) >> 9; int s = g & 7; int ct = g >> 3;
    val = W1[(s * 32 + kn) * 64 + (ct * 16 + nn)];
  }
  wsb[idx] = f2bf(val);
}

// LDS: bufA 32x256 bf16 (stride 512B, swz) | bufB same | wbuf 32x64 bf16 (stride 128B, swz) | ldp f32[32][4]
#define L_BUFB 16384
#define L_WBUF 32768
#define L_LDP  36864
#define L_SIZE 37376

__global__ void __launch_bounds__(256, 3)
invres_main(const float* __restrict__ y, const float* __restrict__ ldj,
            const float* __restrict__ v, const float* __restrict__ b1,
            const float* __restrict__ b2, const float* __restrict__ b3,
            const unsigned short* __restrict__ wsb, float* __restrict__ out) {
  extern __shared__ char smem[];
  char* bufA = smem;
  char* bufB = smem + L_BUFB;
  char* wbuf = smem + L_WBUF;
  float* ldp = (float*)(smem + L_LDP);

  const int tid = threadIdx.x;
  const int lane = tid & 63;
  const int wid = tid >> 6;      // 0..3
  const int l15 = lane & 15, g16 = lane >> 4;
  const int r0 = blockIdx.x * 32;

  const bf16x8* R1 = (const bf16x8*)(wsb + O_R1);
  const bf16x8* R2 = (const bf16x8*)(wsb + O_R2);
  const bf16x8* R3 = (const bf16x8*)(wsb + O_R3);
  const bf16x8* R4 = (const bf16x8*)(wsb + O_R4);
  const bf16x8* R5 = (const bf16x8*)(wsb + O_R5);
  const bf16x8* R6 = (const bf16x8*)(wsb + O_R6);

  // A-fragment (16x16x32) from a 32x256 swizzled LDS buffer
  auto ldsA = [&](const char* buf, int mm, int s) -> bf16x8 {
    int row = mm * 16 + l15;
    unsigned byte = ((unsigned)(s * 64 + g16 * 16)) ^ ((unsigned)(row & 7) << 4);
    return *(const bf16x8*)(buf + row * 512 + byte);
  };
  // D-layout store into a 32x256 swizzled LDS buffer
  auto dstore = [&](char* buf, int mm, int nn, int r, float val) {
    int row = mm * 16 + g16 * 4 + r;
    int col = wid * 64 + nn * 16 + l15;
    *(unsigned short*)(buf + row * 512 + (((unsigned)(col * 2)) ^ ((unsigned)(row & 7) << 4))) = f2bf(val);
  };
  // global A-fragment from y/v (row-major fp32), optional ELU
  auto gA = [&](const float* p, int mm, int s, bool elu) -> bf16x8 {
    const float* q = p + (size_t)(r0 + mm * 16 + l15) * 64 + s * 32 + g16 * 8;
    f32x4 a = *(const f32x4*)q;
    f32x4 b = *(const f32x4*)(q + 4);
    float xv[8] = {a[0], a[1], a[2], a[3], b[0], b[1], b[2], b[3]};
    bf16x8 f;
#pragma unroll
    for (int i = 0; i < 8; i++) {
      float x = xv[i];
      if (elu) x = x > 0.f ? x : (__expf(x) - 1.f);
      f[i] = (short)f2bf(x);
    }
    return f;
  };

  float bb1[4], bb2[4];
#pragma unroll
  for (int nn = 0; nn < 4; nn++) {
    bb1[nn] = b1[wid * 64 + nn * 16 + l15];
    bb2[nn] = b2[wid * 64 + nn * 16 + l15];
  }
  const float bb3 = b3[wid * 16 + l15];

  unsigned d1p[16], d2p[16], d0p[4], v0p[4];
  float ldacc[8];
#pragma unroll
  for (int i = 0; i < 8; i++) ldacc[i] = 0.f;

  // ---------------- G1: a1 = elu(y) @ W1^T + b1 -> bufA, d1 ----------------
  {
    f32x4 acc[2][4] = {};
#pragma unroll
    for (int s = 0; s < 2; s++) {
      bf16x8 a0 = gA(y, 0, s, true);
      bf16x8 a1 = gA(y, 1, s, true);
#pragma unroll
      for (int nn = 0; nn < 4; nn++) {
        bf16x8 B = R1[((wid * 4 + nn) * 2 + s) * 64 + lane];
        acc[0][nn] = MFMA16(a0, B, acc[0][nn]);
        acc[1][nn] = MFMA16(a1, B, acc[1][nn]);
      }
    }
#pragma unroll
    for (int mm = 0; mm < 2; mm++)
#pragma unroll
      for (int nn = 0; nn < 4; nn++)
#pragma unroll
        for (int r = 0; r < 4; r++) {
          float a = acc[mm][nn][r] + bb1[nn];
          float e = __expf(a);
          float h = a > 0.f ? a : (e - 1.f);
          unsigned dd = f2bf(a > 0.f ? 1.f : e);
          dstore(bufA, mm, nn, r, h);
          int idx = (mm * 4 + nn) * 2 + (r >> 1);
          d1p[idx] = (r & 1) ? (d1p[idx] | (dd << 16)) : dd;
        }
  }
  __syncthreads();

  // ---------------- G2: a2 = h1 @ W2^T + b2 -> bufB, d2 ----------------
  {
    f32x4 acc[2][4] = {};
#pragma unroll
    for (int s = 0; s < 8; s++) {
      bf16x8 a0 = ldsA(bufA, 0, s);
      bf16x8 a1 = ldsA(bufA, 1, s);
#pragma unroll
      for (int nn = 0; nn < 4; nn++) {
        bf16x8 B = R2[((wid * 4 + nn) * 8 + s) * 64 + lane];
        acc[0][nn] = MFMA16(a0, B, acc[0][nn]);
        acc[1][nn] = MFMA16(a1, B, acc[1][nn]);
      }
    }
#pragma unroll
    for (int mm = 0; mm < 2; mm++)
#pragma unroll
      for (int nn = 0; nn < 4; nn++)
#pragma unroll
        for (int r = 0; r < 4; r++) {
          float a = acc[mm][nn][r] + bb2[nn];
          float e = __expf(a);
          float h = a > 0.f ? a : (e - 1.f);
          unsigned dd = f2bf(a > 0.f ? 1.f : e);
          dstore(bufB, mm, nn, r, h);
          int idx = (mm * 4 + nn) * 2 + (r >> 1);
          d2p[idx] = (r & 1) ? (d2p[idx] | (dd << 16)) : dd;
        }
  }
  __syncthreads();

  // ---------------- G3: z = y + h2 @ W3^T + b3 ; d0, v0 ----------------
  {
    f32x4 acc[2] = {};
#pragma unroll
    for (int s = 0; s < 8; s++) {
      bf16x8 B = R3[(wid * 8 + s) * 64 + lane];
      acc[0] = MFMA16(ldsA(bufB, 0, s), B, acc[0]);
      acc[1] = MFMA16(ldsA(bufB, 1, s), B, acc[1]);
    }
#pragma unroll
    for (int mm = 0; mm < 2; mm++)
#pragma unroll
      for (int r = 0; r < 4; r++) {
        int row = r0 + mm * 16 + g16 * 4 + r;
        int col = wid * 16 + l15;
        size_t off = (size_t)row * 64 + col;
        float yv = y[off];
        out[off] = yv + acc[mm][r] + bb3;
        unsigned dd = f2bf(yv > 0.f ? 1.f : __expf(yv));
        unsigned vv = f2bf(v[off]);
        int idx = mm * 2 + (r >> 1);
        d0p[idx] = (r & 1) ? (d0p[idx] | (dd << 16)) : dd;
        v0p[idx] = (r & 1) ? (v0p[idx] | (vv << 16)) : vv;
      }
  }

  // ---------------- G4 (k=1): u2 = (v0 @ W3) * d2 -> bufA ----------------
  {
    f32x4 acc[2][4] = {};
#pragma unroll
    for (int s = 0; s < 2; s++) {
      bf16x8 a0 = gA(v, 0, s, false);
      bf16x8 a1 = gA(v, 1, s, false);
#pragma unroll
      for (int nn = 0; nn < 4; nn++) {
        bf16x8 B = R4[((wid * 4 + nn) * 2 + s) * 64 + lane];
        acc[0][nn] = MFMA16(a0, B, acc[0][nn]);
        acc[1][nn] = MFMA16(a1, B, acc[1][nn]);
      }
    }
#pragma unroll
    for (int mm = 0; mm < 2; mm++)
#pragma unroll
      for (int nn = 0; nn < 4; nn++)
#pragma unroll
        for (int r = 0; r < 4; r++) {
          int idx = (mm * 4 + nn) * 2 + (r >> 1);
          float u = acc[mm][nn][r] * bf2f((d2p[idx] >> ((r & 1) * 16)) & 0xffffu);
          dstore(bufA, mm, nn, r, u);
        }
  }
  __syncthreads();

  // ---------------- backward iterations ----------------
  for (int k = 1; k <= 8; ++k) {
    // G5: u1 = (u2 @ W2) * d1 -> bufB
    {
      f32x4 acc[2][4] = {};
#pragma unroll
      for (int s = 0; s < 8; s++) {
        bf16x8 a0 = ldsA(bufA, 0, s);
        bf16x8 a1 = ldsA(bufA, 1, s);
#pragma unroll
        for (int nn = 0; nn < 4; nn++) {
          bf16x8 B = R5[((wid * 4 + nn) * 8 + s) * 64 + lane];
          acc[0][nn] = MFMA16(a0, B, acc[0][nn]);
          acc[1][nn] = MFMA16(a1, B, acc[1][nn]);
        }
      }
#pragma unroll
      for (int mm = 0; mm < 2; mm++)
#pragma unroll
        for (int nn = 0; nn < 4; nn++)
#pragma unroll
          for (int r = 0; r < 4; r++) {
            int idx = (mm * 4 + nn) * 2 + (r >> 1);
            float u = acc[mm][nn][r] * bf2f((d1p[idx] >> ((r & 1) * 16)) & 0xffffu);
            dstore(bufB, mm, nn, r, u);
          }
    }
    __syncthreads();

    // G6: w' = (u1 @ W1) * d0 ; log-det ; w' -> wbuf
    {
      float coef = (k & 1) ? (1.f / (float)k) : (-1.f / (float)k);
      f32x4 acc[2] = {};
#pragma unroll
      for (int s = 0; s < 8; s++) {
        bf16x8 B = R6[(wid * 8 + s) * 64 + lane];
        acc[0] = MFMA16(ldsA(bufB, 0, s), B, acc[0]);
        acc[1] = MFMA16(ldsA(bufB, 1, s), B, acc[1]);
      }
#pragma unroll
      for (int mm = 0; mm < 2; mm++)
#pragma unroll
        for (int r = 0; r < 4; r++) {
          int idx = mm * 2 + (r >> 1);
          float wv = acc[mm][r] * bf2f((d0p[idx] >> ((r & 1) * 16)) & 0xffffu);
          ldacc[mm * 4 + r] += coef * wv * bf2f((v0p[idx] >> ((r & 1) * 16)) & 0xffffu);
          if (k < 8) {
            int row = mm * 16 + g16 * 4 + r;
            int col = wid * 16 + l15;
            *(unsigned short*)(wbuf + row * 128 + (((unsigned)(col * 2)) ^ ((unsigned)(row & 7) << 4))) = f2bf(wv);
          }
        }
    }
    if (k < 8) {
      __syncthreads();
      // G4': u2 = (w' @ W3) * d2 -> bufA
      f32x4 acc[2][4] = {};
#pragma unroll
      for (int s = 0; s < 2; s++) {
        bf16x8 a0, a1;
#pragma unroll
        for (int mm = 0; mm < 2; mm++) {
          int row = mm * 16 + l15;
          unsigned byte = ((unsigned)(s * 64 + g16 * 16)) ^ ((unsigned)(row & 7) << 4);
          bf16x8 a = *(const bf16x8*)(wbuf + row * 128 + byte);
          if (mm == 0) a0 = a; else a1 = a;
        }
#pragma unroll
        for (int nn = 0; nn < 4; nn++) {
          bf16x8 B = R4[((wid * 4 + nn) * 2 + s) * 64 + lane];
          acc[0][nn] = MFMA16(a0, B, acc[0][nn]);
          acc[1][nn] = MFMA16(a1, B, acc[1][nn]);
        }
      }
#pragma unroll
      for (int mm = 0; mm < 2; mm++)
#pragma unroll
        for (int nn = 0; nn < 4; nn++)
#pragma unroll
          for (int r = 0; r < 4; r++) {
            int idx = (mm * 4 + nn) * 2 + (r >> 1);
            float u = acc[mm][nn][r] * bf2f((d2p[idx] >> ((r & 1) * 16)) & 0xffffu);
            dstore(bufA, mm, nn, r, u);
          }
      __syncthreads();
    }
  }

  // ---------------- log-det epilogue ----------------
#pragma unroll
  for (int i = 0; i < 8; i++) {
    float s = ldacc[i];
    s += __shfl_xor(s, 1);
    s += __shfl_xor(s, 2);
    s += __shfl_xor(s, 4);
    s += __shfl_xor(s, 8);
    ldacc[i] = s;
  }
  if (l15 == 0) {
#pragma unroll
    for (int mm = 0; mm < 2; mm++)
#pragma unroll
      for (int r = 0; r < 4; r++) {
        int row = mm * 16 + g16 * 4 + r;
        ldp[row * 4 + wid] = ldacc[mm * 4 + r];
      }
  }
  __syncthreads();
  if (tid < 32) {
    float s = ldp[tid * 4] + ldp[tid * 4 + 1] + ldp[tid * 4 + 2] + ldp[tid * 4 + 3];
    int gb = r0 + tid;
    out[(size_t)BN * 64 + gb] = ldj[gb] + s;
  }
}

extern "C" void kernel_launch(void* const* d_in, const int* in_sizes, int n_in,
                              void* d_out, int out_size, void* d_ws, size_t ws_size,
                              hipStream_t stream) {
  const float* y   = (const float*)d_in[0];
  const float* ldj = (const float*)d_in[1];
  const float* v   = (const float*)d_in[2];
  const float* W1  = (const float*)d_in[3];
  const float* b1  = (const float*)d_in[4];
  const float* W2  = (const float*)d_in[5];
  const float* b2  = (const float*)d_in[6];
  const float* W3  = (const float*)d_in[7];
  const float* b3  = (const float*)d_in[8];
  unsigned short* wsb = (unsigned short*)d_ws;
  float* out = (float*)d_out;

  (void)hipFuncSetAttribute(reinterpret_cast<const void*>(&invres_main),
                            hipFuncAttributeMaxDynamicSharedMemorySize, L_SIZE);

  invres_prep<<<N_WS / 256, 256, 0, stream>>>(W1, W2, W3, wsb);
  invres_main<<<BN / 32, 256, L_SIZE, stream>>>(y, ldj, v, b1, b2, b3, wsb, out);
}

// Round 7
// 3239.715 us; speedup vs baseline: 1.4041x; 1.4041x over previous
//
#include <hip/hip_runtime.h>

#define BN 262144

typedef short bf16x8 __attribute__((ext_vector_type(8)));
typedef float f32x4 __attribute__((ext_vector_type(4)));

#define MFMA16(a,b,c) __builtin_amdgcn_mfma_f32_16x16x32_bf16((a),(b),(c),0,0,0)

__device__ __forceinline__ unsigned short f2bf(float f) {
  union { float f; unsigned int u; } x; x.f = f;
  unsigned int u = x.u + 0x7fffu + ((x.u >> 16) & 1u);
  return (unsigned short)(u >> 16);
}
__device__ __forceinline__ float bf2f(unsigned int h) {
  union { unsigned int u; float f; } x; x.u = h << 16;
  return x.f;
}

// All weight arrays in 16x16x32 B-fragment layout (ushort units):
// elem ((ct*KS+s)*64+lane)*8+j holds B[k][n], n = ct*16+(lane&15), k = s*32+(lane>>4)*8+j
#define O_R1 0        // W1^T: B[k][n]=W1[n*64+k]   K=64  N=256 KS=2
#define O_R2 16384    // W2^T: B[k][n]=W2[n*256+k]  K=256 N=256 KS=8
#define O_R3 81920    // W3^T: B[k][n]=W3[n*256+k]  K=256 N=64  KS=8
#define O_R4 98304    // W3  : B[k][n]=W3[k*256+n]  K=64  N=256 KS=2
#define O_R5 114688   // W2  : B[k][n]=W2[k*256+n]  K=256 N=256 KS=8
#define O_R6 180224   // W1  : B[k][n]=W1[k*64+n]   K=256 N=64  KS=8
#define N_WS 196608

__global__ void invres_prep(const float* __restrict__ W1, const float* __restrict__ W2,
                            const float* __restrict__ W3, unsigned short* __restrict__ wsb) {
  int idx = blockIdx.x * 256 + threadIdx.x;
  if (idx >= N_WS) return;
  int j = idx & 7;
  int lane = (idx >> 3) & 63;
  int nn = lane & 15, kn = (lane >> 4) * 8 + j;
  float val;
  if (idx < O_R2) {                // R1, KS=2
    int g = idx >> 9; int s = g & 1; int ct = g >> 1;
    val = W1[(ct * 16 + nn) * 64 + (s * 32 + kn)];
  } else if (idx < O_R3) {         // R2, KS=8
    int g = (idx - O_R2) >> 9; int s = g & 7; int ct = g >> 3;
    val = W2[(ct * 16 + nn) * 256 + (s * 32 + kn)];
  } else if (idx < O_R4) {         // R3, KS=8
    int g = (idx - O_R3) >> 9; int s = g & 7; int ct = g >> 3;
    val = W3[(ct * 16 + nn) * 256 + (s * 32 + kn)];
  } else if (idx < O_R5) {         // R4, KS=2
    int g = (idx - O_R4) >> 9; int s = g & 1; int ct = g >> 1;
    val = W3[(s * 32 + kn) * 256 + (ct * 16 + nn)];
  } else if (idx < O_R6) {         // R5, KS=8
    int g = (idx - O_R5) >> 9; int s = g & 7; int ct = g >> 3;
    val = W2[(s * 32 + kn) * 256 + (ct * 16 + nn)];
  } else {                         // R6, KS=8
    int g = (idx - O_R6) >> 9; int s = g & 7; int ct = g >> 3;
    val = W1[(s * 32 + kn) * 64 + (ct * 16 + nn)];
  }
  wsb[idx] = f2bf(val);
}

// LDS: bufA 32x256 bf16 (stride 512B, swz) | bufB same | wbuf 32x64 bf16 (stride 128B, swz) | ldp f32[32][4]
#define L_BUFB 16384
#define L_WBUF 32768
#define L_LDP  36864
#define L_SIZE 37376

__global__ void __launch_bounds__(512, 4)
invres_main(const float* __restrict__ y, const float* __restrict__ ldj,
            const float* __restrict__ v, const float* __restrict__ b1,
            const float* __restrict__ b2, const float* __restrict__ b3,
            const unsigned short* __restrict__ wsb, float* __restrict__ out) {
  extern __shared__ char smem[];
  char* bufA = smem;
  char* bufB = smem + L_BUFB;
  char* wbuf = smem + L_WBUF;
  float* ldp = (float*)(smem + L_LDP);

  const int tid = threadIdx.x;
  const int lane = tid & 63;
  const int wid = tid >> 6;          // 0..7
  const int l15 = lane & 15, g16 = lane >> 4;
  const int ct0 = wid * 2;           // wide: this wave owns col tiles ct0, ct0+1 (32 cols)
  const int mh = wid >> 2;           // narrow: row half (16 rows)
  const int ctn = wid & 3;           // narrow: col tile (16 cols)
  const int r0 = blockIdx.x * 32;

  const bf16x8* R1 = (const bf16x8*)(wsb + O_R1);
  const bf16x8* R2 = (const bf16x8*)(wsb + O_R2);
  const bf16x8* R3 = (const bf16x8*)(wsb + O_R3);
  const bf16x8* R4 = (const bf16x8*)(wsb + O_R4);
  const bf16x8* R5 = (const bf16x8*)(wsb + O_R5);
  const bf16x8* R6 = (const bf16x8*)(wsb + O_R6);

  // A-fragment (16x16x32) from 32x256 swizzled LDS buffer
  auto ldsA = [&](const char* buf, int mm, int s) -> bf16x8 {
    int row = mm * 16 + l15;
    unsigned byte = ((unsigned)(s * 64 + g16 * 16)) ^ ((unsigned)(row & 7) << 4);
    return *(const bf16x8*)(buf + row * 512 + byte);
  };
  // D-layout store into 32x256 swizzled LDS buffer (wide phases)
  auto dstoreW = [&](char* buf, int mm, int cc, int r, float val) {
    int row = mm * 16 + g16 * 4 + r;
    int col = (ct0 + cc) * 16 + l15;
    *(unsigned short*)(buf + row * 512 + (((unsigned)(col * 2)) ^ ((unsigned)(row & 7) << 4))) = f2bf(val);
  };
  // global A-fragment from y/v (row-major fp32)
  auto gA = [&](const float* p, int mm, int s, bool elu, bool nt) -> bf16x8 {
    const float* q = p + (size_t)(r0 + mm * 16 + l15) * 64 + s * 32 + g16 * 8;
    f32x4 a, b;
    if (nt) { a = __builtin_nontemporal_load((const f32x4*)q); b = __builtin_nontemporal_load((const f32x4*)(q + 4)); }
    else    { a = *(const f32x4*)q; b = *(const f32x4*)(q + 4); }
    float xv[8] = {a[0], a[1], a[2], a[3], b[0], b[1], b[2], b[3]};
    bf16x8 f;
#pragma unroll
    for (int i = 0; i < 8; i++) {
      float x = xv[i];
      if (elu) x = x > 0.f ? x : (__expf(x) - 1.f);
      f[i] = (short)f2bf(x);
    }
    return f;
  };

  float bb1[2], bb2[2];
#pragma unroll
  for (int cc = 0; cc < 2; cc++) {
    bb1[cc] = b1[(ct0 + cc) * 16 + l15];
    bb2[cc] = b2[(ct0 + cc) * 16 + l15];
  }
  const float bb3 = b3[ctn * 16 + l15];

  unsigned d1p[8], d2p[8], d0p[2], v0p[2];
  float ldacc[4] = {0.f, 0.f, 0.f, 0.f};

  // ---------------- G1: a1 = elu(y) @ W1^T + b1 -> bufA, d1 ----------------
  {
    f32x4 acc[2][2] = {};
#pragma unroll
    for (int s = 0; s < 2; s++) {
      bf16x8 a0 = gA(y, 0, s, true, false);
      bf16x8 a1 = gA(y, 1, s, true, false);
#pragma unroll
      for (int cc = 0; cc < 2; cc++) {
        bf16x8 B = R1[((ct0 + cc) * 2 + s) * 64 + lane];
        acc[0][cc] = MFMA16(a0, B, acc[0][cc]);
        acc[1][cc] = MFMA16(a1, B, acc[1][cc]);
      }
    }
#pragma unroll
    for (int mm = 0; mm < 2; mm++)
#pragma unroll
      for (int cc = 0; cc < 2; cc++)
#pragma unroll
        for (int r = 0; r < 4; r++) {
          float a = acc[mm][cc][r] + bb1[cc];
          float e = __expf(a);
          float h = a > 0.f ? a : (e - 1.f);
          unsigned dd = f2bf(a > 0.f ? 1.f : e);
          dstoreW(bufA, mm, cc, r, h);
          int idx = (mm * 2 + cc) * 2 + (r >> 1);
          d1p[idx] = (r & 1) ? (d1p[idx] | (dd << 16)) : dd;
        }
  }
  __syncthreads();

  // ---------------- G2: a2 = h1 @ W2^T + b2 -> bufB, d2 ----------------
  {
    f32x4 acc[2][2] = {};
#pragma unroll
    for (int s = 0; s < 8; s++) {
      bf16x8 a0 = ldsA(bufA, 0, s);
      bf16x8 a1 = ldsA(bufA, 1, s);
#pragma unroll
      for (int cc = 0; cc < 2; cc++) {
        bf16x8 B = R2[((ct0 + cc) * 8 + s) * 64 + lane];
        acc[0][cc] = MFMA16(a0, B, acc[0][cc]);
        acc[1][cc] = MFMA16(a1, B, acc[1][cc]);
      }
    }
#pragma unroll
    for (int mm = 0; mm < 2; mm++)
#pragma unroll
      for (int cc = 0; cc < 2; cc++)
#pragma unroll
        for (int r = 0; r < 4; r++) {
          float a = acc[mm][cc][r] + bb2[cc];
          float e = __expf(a);
          float h = a > 0.f ? a : (e - 1.f);
          unsigned dd = f2bf(a > 0.f ? 1.f : e);
          dstoreW(bufB, mm, cc, r, h);
          int idx = (mm * 2 + cc) * 2 + (r >> 1);
          d2p[idx] = (r & 1) ? (d2p[idx] | (dd << 16)) : dd;
        }
  }
  __syncthreads();

  // ---------------- G3: z = y + h2 @ W3^T + b3 ; d0, v0 ----------------
  {
    f32x4 acc = {};
#pragma unroll
    for (int s = 0; s < 8; s++)
      acc = MFMA16(ldsA(bufB, mh, s), R3[(ctn * 8 + s) * 64 + lane], acc);
#pragma unroll
    for (int r = 0; r < 4; r++) {
      int row = r0 + mh * 16 + g16 * 4 + r;
      int col = ctn * 16 + l15;
      size_t off = (size_t)row * 64 + col;
      float yv = y[off];
      __builtin_nontemporal_store(yv + acc[r] + bb3, out + off);
      unsigned dd = f2bf(yv > 0.f ? 1.f : __expf(yv));
      unsigned vv = f2bf(v[off]);
      d0p[r >> 1] = (r & 1) ? (d0p[r >> 1] | (dd << 16)) : dd;
      v0p[r >> 1] = (r & 1) ? (v0p[r >> 1] | (vv << 16)) : vv;
    }
  }

  // ---------------- G4 (k=1): u2 = (v0 @ W3) * d2 -> bufA ----------------
  {
    f32x4 acc[2][2] = {};
#pragma unroll
    for (int s = 0; s < 2; s++) {
      bf16x8 a0 = gA(v, 0, s, false, true);
      bf16x8 a1 = gA(v, 1, s, false, true);
#pragma unroll
      for (int cc = 0; cc < 2; cc++) {
        bf16x8 B = R4[((ct0 + cc) * 2 + s) * 64 + lane];
        acc[0][cc] = MFMA16(a0, B, acc[0][cc]);
        acc[1][cc] = MFMA16(a1, B, acc[1][cc]);
      }
    }
#pragma unroll
    for (int mm = 0; mm < 2; mm++)
#pragma unroll
      for (int cc = 0; cc < 2; cc++)
#pragma unroll
        for (int r = 0; r < 4; r++) {
          int idx = (mm * 2 + cc) * 2 + (r >> 1);
          float u = acc[mm][cc][r] * bf2f((d2p[idx] >> ((r & 1) * 16)) & 0xffffu);
          dstoreW(bufA, mm, cc, r, u);
        }
  }
  __syncthreads();

  // ---------------- backward iterations ----------------
  for (int k = 1; k <= 8; ++k) {
    // G5: u1 = (u2 @ W2) * d1 -> bufB
    {
      f32x4 acc[2][2] = {};
#pragma unroll
      for (int s = 0; s < 8; s++) {
        bf16x8 a0 = ldsA(bufA, 0, s);
        bf16x8 a1 = ldsA(bufA, 1, s);
#pragma unroll
        for (int cc = 0; cc < 2; cc++) {
          bf16x8 B = R5[((ct0 + cc) * 8 + s) * 64 + lane];
          acc[0][cc] = MFMA16(a0, B, acc[0][cc]);
          acc[1][cc] = MFMA16(a1, B, acc[1][cc]);
        }
      }
#pragma unroll
      for (int mm = 0; mm < 2; mm++)
#pragma unroll
        for (int cc = 0; cc < 2; cc++)
#pragma unroll
          for (int r = 0; r < 4; r++) {
            int idx = (mm * 2 + cc) * 2 + (r >> 1);
            float u = acc[mm][cc][r] * bf2f((d1p[idx] >> ((r & 1) * 16)) & 0xffffu);
            dstoreW(bufB, mm, cc, r, u);
          }
    }
    __syncthreads();

    // G6: w' = (u1 @ W1) * d0 ; log-det ; w' -> wbuf
    {
      float coef = (k & 1) ? (1.f / (float)k) : (-1.f / (float)k);
      f32x4 acc = {};
#pragma unroll
      for (int s = 0; s < 8; s++)
        acc = MFMA16(ldsA(bufB, mh, s), R6[(ctn * 8 + s) * 64 + lane], acc);
#pragma unroll
      for (int r = 0; r < 4; r++) {
        float wv = acc[r] * bf2f((d0p[r >> 1] >> ((r & 1) * 16)) & 0xffffu);
        ldacc[r] += coef * wv * bf2f((v0p[r >> 1] >> ((r & 1) * 16)) & 0xffffu);
        if (k < 8) {
          int row = mh * 16 + g16 * 4 + r;
          int col = ctn * 16 + l15;
          *(unsigned short*)(wbuf + row * 128 + (((unsigned)(col * 2)) ^ ((unsigned)(row & 7) << 4))) = f2bf(wv);
        }
      }
    }
    if (k < 8) {
      __syncthreads();
      // G4': u2 = (w' @ W3) * d2 -> bufA
      f32x4 acc[2][2] = {};
#pragma unroll
      for (int s = 0; s < 2; s++) {
        bf16x8 a0, a1;
#pragma unroll
        for (int mm = 0; mm < 2; mm++) {
          int row = mm * 16 + l15;
          unsigned byte = ((unsigned)(s * 64 + g16 * 16)) ^ ((unsigned)(row & 7) << 4);
          bf16x8 a = *(const bf16x8*)(wbuf + row * 128 + byte);
          if (mm == 0) a0 = a; else a1 = a;
        }
#pragma unroll
        for (int cc = 0; cc < 2; cc++) {
          bf16x8 B = R4[((ct0 + cc) * 2 + s) * 64 + lane];
          acc[0][cc] = MFMA16(a0, B, acc[0][cc]);
          acc[1][cc] = MFMA16(a1, B, acc[1][cc]);
        }
      }
#pragma unroll
      for (int mm = 0; mm < 2; mm++)
#pragma unroll
        for (int cc = 0; cc < 2; cc++)
#pragma unroll
          for (int r = 0; r < 4; r++) {
            int idx = (mm * 2 + cc) * 2 + (r >> 1);
            float u = acc[mm][cc][r] * bf2f((d2p[idx] >> ((r & 1) * 16)) & 0xffffu);
            dstoreW(bufA, mm, cc, r, u);
          }
      __syncthreads();
    }
  }

  // ---------------- log-det epilogue ----------------
#pragma unroll
  for (int r = 0; r < 4; r++) {
    float s = ldacc[r];
    s += __shfl_xor(s, 1);
    s += __shfl_xor(s, 2);
    s += __shfl_xor(s, 4);
    s += __shfl_xor(s, 8);
    ldacc[r] = s;
  }
  if (l15 == 0) {
#pragma unroll
    for (int r = 0; r < 4; r++) {
      int row = mh * 16 + g16 * 4 + r;
      ldp[row * 4 + ctn] = ldacc[r];
    }
  }
  __syncthreads();
  if (tid < 32) {
    float s = ldp[tid * 4] + ldp[tid * 4 + 1] + ldp[tid * 4 + 2] + ldp[tid * 4 + 3];
    int gb = r0 + tid;
    __builtin_nontemporal_store(ldj[gb] + s, out + (size_t)BN * 64 + gb);
  }
}

extern "C" void kernel_launch(void* const* d_in, const int* in_sizes, int n_in,
                              void* d_out, int out_size, void* d_ws, size_t ws_size,
                              hipStream_t stream) {
  const float* y   = (const float*)d_in[0];
  const float* ldj = (const float*)d_in[1];
  const float* v   = (const float*)d_in[2];
  const float* W1  = (const float*)d_in[3];
  const float* b1  = (const float*)d_in[4];
  const float* W2  = (const float*)d_in[5];
  const float* b2  = (const float*)d_in[6];
  const float* W3  = (const float*)d_in[7];
  const float* b3  = (const float*)d_in[8];
  unsigned short* wsb = (unsigned short*)d_ws;
  float* out = (float*)d_out;

  (void)hipFuncSetAttribute(reinterpret_cast<const void*>(&invres_main),
                            hipFuncAttributeMaxDynamicSharedMemorySize, L_SIZE);

  invres_prep<<<N_WS / 256, 256, 0, stream>>>(W1, W2, W3, wsb);
  invres_main<<<BN / 32, 512, L_SIZE, stream>>>(y, ldj, v, b1, b2, b3, wsb, out);
}

// Round 8
// 2185.584 us; speedup vs baseline: 2.0813x; 1.4823x over previous
//
#include <hip/hip_runtime.h>

#define BN 262144

typedef short bf16x8 __attribute__((ext_vector_type(8)));
typedef float f32x4 __attribute__((ext_vector_type(4)));

#define MFMA16(a,b,c) __builtin_amdgcn_mfma_f32_16x16x32_bf16((a),(b),(c),0,0,0)

__device__ __forceinline__ unsigned short f2bf(float f) {
  union { float f; unsigned int u; } x; x.f = f;
  unsigned int u = x.u + 0x7fffu + ((x.u >> 16) & 1u);
  return (unsigned short)(u >> 16);
}
__device__ __forceinline__ float bf2f(unsigned int h) {
  union { unsigned int u; float f; } x; x.u = h << 16;
  return x.f;
}

// All weight arrays in 16x16x32 B-fragment layout (ushort units):
// elem ((ct*KS+s)*64+lane)*8+j holds B[k][n], n = ct*16+(lane&15), k = s*32+(lane>>4)*8+j
#define O_R1 0        // W1^T: B[k][n]=W1[n*64+k]   K=64  N=256 KS=2
#define O_R2 16384    // W2^T: B[k][n]=W2[n*256+k]  K=256 N=256 KS=8
#define O_R3 81920    // W3^T: B[k][n]=W3[n*256+k]  K=256 N=64  KS=8
#define O_R4 98304    // W3  : B[k][n]=W3[k*256+n]  K=64  N=256 KS=2
#define O_R5 114688   // W2  : B[k][n]=W2[k*256+n]  K=256 N=256 KS=8
#define O_R6 180224   // W1  : B[k][n]=W1[k*64+n]   K=256 N=64  KS=8
#define N_WS 196608

__global__ void invres_prep(const float* __restrict__ W1, const float* __restrict__ W2,
                            const float* __restrict__ W3, unsigned short* __restrict__ wsb) {
  int idx = blockIdx.x * 256 + threadIdx.x;
  if (idx >= N_WS) return;
  int j = idx & 7;
  int lane = (idx >> 3) & 63;
  int nn = lane & 15, kn = (lane >> 4) * 8 + j;
  float val;
  if (idx < O_R2) {                // R1, KS=2
    int g = idx >> 9; int s = g & 1; int ct = g >> 1;
    val = W1[(ct * 16 + nn) * 64 + (s * 32 + kn)];
  } else if (idx < O_R3) {         // R2, KS=8
    int g = (idx - O_R2) >> 9; int s = g & 7; int ct = g >> 3;
    val = W2[(ct * 16 + nn) * 256 + (s * 32 + kn)];
  } else if (idx < O_R4) {         // R3, KS=8
    int g = (idx - O_R3) >> 9; int s = g & 7; int ct = g >> 3;
    val = W3[(ct * 16 + nn) * 256 + (s * 32 + kn)];
  } else if (idx < O_R5) {         // R4, KS=2
    int g = (idx - O_R4) >> 9; int s = g & 1; int ct = g >> 1;
    val = W3[(s * 32 + kn) * 256 + (ct * 16 + nn)];
  } else if (idx < O_R6) {         // R5, KS=8
    int g = (idx - O_R5) >> 9; int s = g & 7; int ct = g >> 3;
    val = W2[(s * 32 + kn) * 256 + (ct * 16 + nn)];
  } else {                         // R6, KS=8
    int g = (idx - O_R6) >> 9; int s = g & 7; int ct = g >> 3;
    val = W1[(s * 32 + kn) * 64 + (ct * 16 + nn)];
  }
  wsb[idx] = f2bf(val);
}

// LDS (per block, M=32):
//  H1  32x256 bf16 swz  (16K) - h1, written G1; frags for G2; mask scalars for G5
//  H2  32x256 bf16 swz  (16K) - h2, written G2; frags for G3; mask scalars for G4/G4'
//  U2  32x256 bf16 swz  (16K) - u2, written G4/G4'; frags for G5
//  U1  32x256 bf16 swz  (16K) - u1, written G5; frags for G6
//  WB  32x64  bf16 swz  (4K)  - w,  written G6; frags for G4'
//  LDP f32[32][4]       (512B)
#define L_H2  16384
#define L_U2  32768
#define L_U1  49152
#define L_WB  65536
#define L_LDP 69632
#define L_SIZE 70144

__global__ void __launch_bounds__(512, 4)
invres_main(const float* __restrict__ y, const float* __restrict__ ldj,
            const float* __restrict__ v, const float* __restrict__ b1,
            const float* __restrict__ b2, const float* __restrict__ b3,
            const unsigned short* __restrict__ wsb, float* __restrict__ out) {
  extern __shared__ char smem[];
  char* H1 = smem;
  char* H2 = smem + L_H2;
  char* U2 = smem + L_U2;
  char* U1 = smem + L_U1;
  char* WB = smem + L_WB;
  float* ldp = (float*)(smem + L_LDP);

  const int tid = threadIdx.x;
  const int lane = tid & 63;
  const int wid = tid >> 6;          // 0..7
  const int l15 = lane & 15, g16 = lane >> 4;
  const int ct0 = wid * 2;           // wide: col tiles ct0, ct0+1 (32 cols)
  const int mh = wid >> 2;           // narrow: row half (16 rows)
  const int ctn = wid & 3;           // narrow: col tile (16 cols)
  const int r0 = blockIdx.x * 32;

  const bf16x8* R1 = (const bf16x8*)(wsb + O_R1);
  const bf16x8* R2 = (const bf16x8*)(wsb + O_R2);
  const bf16x8* R3 = (const bf16x8*)(wsb + O_R3);
  const bf16x8* R4 = (const bf16x8*)(wsb + O_R4);
  const bf16x8* R5 = (const bf16x8*)(wsb + O_R5);
  const bf16x8* R6 = (const bf16x8*)(wsb + O_R6);

  // A-fragment (16x16x32) from 32x256 swizzled LDS buffer
  auto ldsA = [&](const char* buf, int mm, int s) -> bf16x8 {
    int row = mm * 16 + l15;
    unsigned byte = ((unsigned)(s * 64 + g16 * 16)) ^ ((unsigned)(row & 7) << 4);
    return *(const bf16x8*)(buf + row * 512 + byte);
  };
  // D-layout store into 32x256 swizzled LDS buffer (wide phases)
  auto dstoreW = [&](char* buf, int mm, int cc, int r, float val) {
    int row = mm * 16 + g16 * 4 + r;
    int col = (ct0 + cc) * 16 + l15;
    *(unsigned short*)(buf + row * 512 + (((unsigned)(col * 2)) ^ ((unsigned)(row & 7) << 4))) = f2bf(val);
  };
  // ELU' mask from stored activation h: d = h>0 ? 1 : h+1
  auto maskW = [&](const char* buf, int mm, int cc, int r) -> float {
    int row = mm * 16 + g16 * 4 + r;
    int col = (ct0 + cc) * 16 + l15;
    unsigned short hv = *(const unsigned short*)(buf + row * 512 + (((unsigned)(col * 2)) ^ ((unsigned)(row & 7) << 4)));
    float h = bf2f(hv);
    return h > 0.f ? 1.f : h + 1.f;
  };
  // global A-fragment from y/v (row-major fp32), NT
  auto gA = [&](const float* p, int mm, int s, bool elu) -> bf16x8 {
    const float* q = p + (size_t)(r0 + mm * 16 + l15) * 64 + s * 32 + g16 * 8;
    f32x4 a = __builtin_nontemporal_load((const f32x4*)q);
    f32x4 b = __builtin_nontemporal_load((const f32x4*)(q + 4));
    float xv[8] = {a[0], a[1], a[2], a[3], b[0], b[1], b[2], b[3]};
    bf16x8 f;
#pragma unroll
    for (int i = 0; i < 8; i++) {
      float x = xv[i];
      if (elu) x = x > 0.f ? x : (__expf(x) - 1.f);
      f[i] = (short)f2bf(x);
    }
    return f;
  };

  float bb1[2], bb2[2];
#pragma unroll
  for (int cc = 0; cc < 2; cc++) {
    bb1[cc] = b1[(ct0 + cc) * 16 + l15];
    bb2[cc] = b2[(ct0 + cc) * 16 + l15];
  }
  const float bb3 = b3[ctn * 16 + l15];

  unsigned d0p[2], v0p[2];
  float ldacc[4] = {0.f, 0.f, 0.f, 0.f};

  // ---------------- G1: h1 = elu(elu(y) @ W1^T + b1) -> H1 ----------------
  {
    f32x4 acc[2][2] = {};
#pragma unroll
    for (int s = 0; s < 2; s++) {
      bf16x8 a0 = gA(y, 0, s, true);
      bf16x8 a1 = gA(y, 1, s, true);
#pragma unroll
      for (int cc = 0; cc < 2; cc++) {
        bf16x8 B = R1[((ct0 + cc) * 2 + s) * 64 + lane];
        acc[0][cc] = MFMA16(a0, B, acc[0][cc]);
        acc[1][cc] = MFMA16(a1, B, acc[1][cc]);
      }
    }
#pragma unroll
    for (int mm = 0; mm < 2; mm++)
#pragma unroll
      for (int cc = 0; cc < 2; cc++)
#pragma unroll
        for (int r = 0; r < 4; r++) {
          float a = acc[mm][cc][r] + bb1[cc];
          float h = a > 0.f ? a : (__expf(a) - 1.f);
          dstoreW(H1, mm, cc, r, h);
        }
  }
  __syncthreads();

  // ---------------- G2: h2 = elu(h1 @ W2^T + b2) -> H2 ----------------
  {
    f32x4 acc[2][2] = {};
#pragma unroll
    for (int s = 0; s < 8; s++) {
      bf16x8 a0 = ldsA(H1, 0, s);
      bf16x8 a1 = ldsA(H1, 1, s);
#pragma unroll
      for (int cc = 0; cc < 2; cc++) {
        bf16x8 B = R2[((ct0 + cc) * 8 + s) * 64 + lane];
        acc[0][cc] = MFMA16(a0, B, acc[0][cc]);
        acc[1][cc] = MFMA16(a1, B, acc[1][cc]);
      }
    }
#pragma unroll
    for (int mm = 0; mm < 2; mm++)
#pragma unroll
      for (int cc = 0; cc < 2; cc++)
#pragma unroll
        for (int r = 0; r < 4; r++) {
          float a = acc[mm][cc][r] + bb2[cc];
          float h = a > 0.f ? a : (__expf(a) - 1.f);
          dstoreW(H2, mm, cc, r, h);
        }
  }
  __syncthreads();

  // ---------------- G3: z = y + h2 @ W3^T + b3 ; d0, v0 ----------------
  {
    f32x4 acc = {};
#pragma unroll
    for (int s = 0; s < 8; s++)
      acc = MFMA16(ldsA(H2, mh, s), R3[(ctn * 8 + s) * 64 + lane], acc);
#pragma unroll
    for (int r = 0; r < 4; r++) {
      int row = r0 + mh * 16 + g16 * 4 + r;
      int col = ctn * 16 + l15;
      size_t off = (size_t)row * 64 + col;
      float yv = __builtin_nontemporal_load(y + off);
      __builtin_nontemporal_store(yv + acc[r] + bb3, out + off);
      unsigned dd = f2bf(yv > 0.f ? 1.f : __expf(yv));
      unsigned vv = f2bf(__builtin_nontemporal_load(v + off));
      d0p[r >> 1] = (r & 1) ? (d0p[r >> 1] | (dd << 16)) : dd;
      v0p[r >> 1] = (r & 1) ? (v0p[r >> 1] | (vv << 16)) : vv;
    }
  }

  // ---------------- G4 (k=1): u2 = (v0 @ W3) * d2 -> U2 ----------------
  {
    f32x4 acc[2][2] = {};
#pragma unroll
    for (int s = 0; s < 2; s++) {
      bf16x8 a0 = gA(v, 0, s, false);
      bf16x8 a1 = gA(v, 1, s, false);
#pragma unroll
      for (int cc = 0; cc < 2; cc++) {
        bf16x8 B = R4[((ct0 + cc) * 2 + s) * 64 + lane];
        acc[0][cc] = MFMA16(a0, B, acc[0][cc]);
        acc[1][cc] = MFMA16(a1, B, acc[1][cc]);
      }
    }
#pragma unroll
    for (int mm = 0; mm < 2; mm++)
#pragma unroll
      for (int cc = 0; cc < 2; cc++)
#pragma unroll
        for (int r = 0; r < 4; r++) {
          float u = acc[mm][cc][r] * maskW(H2, mm, cc, r);
          dstoreW(U2, mm, cc, r, u);
        }
  }
  __syncthreads();

  // ---------------- backward iterations ----------------
  for (int k = 1; k <= 8; ++k) {
    // G5: u1 = (u2 @ W2) * d1 -> U1   (d1 from H1)
    {
      f32x4 acc[2][2] = {};
#pragma unroll
      for (int s = 0; s < 8; s++) {
        bf16x8 a0 = ldsA(U2, 0, s);
        bf16x8 a1 = ldsA(U2, 1, s);
#pragma unroll
        for (int cc = 0; cc < 2; cc++) {
          bf16x8 B = R5[((ct0 + cc) * 8 + s) * 64 + lane];
          acc[0][cc] = MFMA16(a0, B, acc[0][cc]);
          acc[1][cc] = MFMA16(a1, B, acc[1][cc]);
        }
      }
#pragma unroll
      for (int mm = 0; mm < 2; mm++)
#pragma unroll
        for (int cc = 0; cc < 2; cc++)
#pragma unroll
          for (int r = 0; r < 4; r++) {
            float u = acc[mm][cc][r] * maskW(H1, mm, cc, r);
            dstoreW(U1, mm, cc, r, u);
          }
    }
    __syncthreads();

    // G6: w' = (u1 @ W1) * d0 ; log-det ; w' -> WB
    {
      float coef = (k & 1) ? (1.f / (float)k) : (-1.f / (float)k);
      f32x4 acc = {};
#pragma unroll
      for (int s = 0; s < 8; s++)
        acc = MFMA16(ldsA(U1, mh, s), R6[(ctn * 8 + s) * 64 + lane], acc);
#pragma unroll
      for (int r = 0; r < 4; r++) {
        float wv = acc[r] * bf2f((d0p[r >> 1] >> ((r & 1) * 16)) & 0xffffu);
        ldacc[r] += coef * wv * bf2f((v0p[r >> 1] >> ((r & 1) * 16)) & 0xffffu);
        if (k < 8) {
          int row = mh * 16 + g16 * 4 + r;
          int col = ctn * 16 + l15;
          *(unsigned short*)(WB + row * 128 + (((unsigned)(col * 2)) ^ ((unsigned)(row & 7) << 4))) = f2bf(wv);
        }
      }
    }
    if (k < 8) {
      __syncthreads();
      // G4': u2 = (w' @ W3) * d2 -> U2   (d2 from H2)
      f32x4 acc[2][2] = {};
#pragma unroll
      for (int s = 0; s < 2; s++) {
        bf16x8 a0, a1;
#pragma unroll
        for (int mm = 0; mm < 2; mm++) {
          int row = mm * 16 + l15;
          unsigned byte = ((unsigned)(s * 64 + g16 * 16)) ^ ((unsigned)(row & 7) << 4);
          bf16x8 a = *(const bf16x8*)(WB + row * 128 + byte);
          if (mm == 0) a0 = a; else a1 = a;
        }
#pragma unroll
        for (int cc = 0; cc < 2; cc++) {
          bf16x8 B = R4[((ct0 + cc) * 2 + s) * 64 + lane];
          acc[0][cc] = MFMA16(a0, B, acc[0][cc]);
          acc[1][cc] = MFMA16(a1, B, acc[1][cc]);
        }
      }
#pragma unroll
      for (int mm = 0; mm < 2; mm++)
#pragma unroll
        for (int cc = 0; cc < 2; cc++)
#pragma unroll
          for (int r = 0; r < 4; r++) {
            float u = acc[mm][cc][r] * maskW(H2, mm, cc, r);
            dstoreW(U2, mm, cc, r, u);
          }
      __syncthreads();
    }
  }

  // ---------------- log-det epilogue ----------------
#pragma unroll
  for (int r = 0; r < 4; r++) {
    float s = ldacc[r];
    s += __shfl_xor(s, 1);
    s += __shfl_xor(s, 2);
    s += __shfl_xor(s, 4);
    s += __shfl_xor(s, 8);
    ldacc[r] = s;
  }
  if (l15 == 0) {
#pragma unroll
    for (int r = 0; r < 4; r++) {
      int row = mh * 16 + g16 * 4 + r;
      ldp[row * 4 + ctn] = ldacc[r];
    }
  }
  __syncthreads();
  if (tid < 32) {
    float s = ldp[tid * 4] + ldp[tid * 4 + 1] + ldp[tid * 4 + 2] + ldp[tid * 4 + 3];
    int gb = r0 + tid;
    __builtin_nontemporal_store(ldj[gb] + s, out + (size_t)BN * 64 + gb);
  }
}

extern "C" void kernel_launch(void* const* d_in, const int* in_sizes, int n_in,
                              void* d_out, int out_size, void* d_ws, size_t ws_size,
                              hipStream_t stream) {
  const float* y   = (const float*)d_in[0];
  const float* ldj = (const float*)d_in[1];
  const float* v   = (const float*)d_in[2];
  const float* W1  = (const float*)d_in[3];
  const float* b1  = (const float*)d_in[4];
  const float* W2  = (const float*)d_in[5];
  const float* b2  = (const float*)d_in[6];
  const float* W3  = (const float*)d_in[7];
  const float* b3  = (const float*)d_in[8];
  unsigned short* wsb = (unsigned short*)d_ws;
  float* out = (float*)d_out;

  (void)hipFuncSetAttribute(reinterpret_cast<const void*>(&invres_main),
                            hipFuncAttributeMaxDynamicSharedMemorySize, L_SIZE);

  invres_prep<<<N_WS / 256, 256, 0, stream>>>(W1, W2, W3, wsb);
  invres_main<<<BN / 32, 512, L_SIZE, stream>>>(y, ldj, v, b1, b2, b3, wsb, out);
}

// Round 9
// 933.000 us; speedup vs baseline: 4.8756x; 2.3425x over previous
//
#include <hip/hip_runtime.h>

#define BN 262144

typedef short bf16x8 __attribute__((ext_vector_type(8)));
typedef float f32x4 __attribute__((ext_vector_type(4)));

#define MFMA16(a,b,c) __builtin_amdgcn_mfma_f32_16x16x32_bf16((a),(b),(c),0,0,0)

__device__ __forceinline__ unsigned short f2bf(float f) {
  union { float f; unsigned int u; } x; x.f = f;
  unsigned int u = x.u + 0x7fffu + ((x.u >> 16) & 1u);
  return (unsigned short)(u >> 16);
}
__device__ __forceinline__ float bf2f(unsigned int h) {
  union { unsigned int u; float f; } x; x.u = h << 16;
  return x.f;
}

// All weight arrays in 16x16x32 B-fragment layout (ushort units):
// elem ((ct*KS+s)*64+lane)*8+j holds B[k][n], n = ct*16+(lane&15), k = s*32+(lane>>4)*8+j
#define O_R1 0        // W1^T: B[k][n]=W1[n*64+k]   K=64  N=256 KS=2
#define O_R2 16384    // W2^T: B[k][n]=W2[n*256+k]  K=256 N=256 KS=8
#define O_R3 81920    // W3^T: B[k][n]=W3[n*256+k]  K=256 N=64  KS=8
#define O_R4 98304    // W3  : B[k][n]=W3[k*256+n]  K=64  N=256 KS=2
#define O_R5 114688   // W2  : B[k][n]=W2[k*256+n]  K=256 N=256 KS=8
#define O_R6 180224   // W1  : B[k][n]=W1[k*64+n]   K=256 N=64  KS=8
#define N_WS 196608

__global__ void invres_prep(const float* __restrict__ W1, const float* __restrict__ W2,
                            const float* __restrict__ W3, unsigned short* __restrict__ wsb) {
  int idx = blockIdx.x * 256 + threadIdx.x;
  if (idx >= N_WS) return;
  int j = idx & 7;
  int lane = (idx >> 3) & 63;
  int nn = lane & 15, kn = (lane >> 4) * 8 + j;
  float val;
  if (idx < O_R2) {                // R1, KS=2
    int g = idx >> 9; int s = g & 1; int ct = g >> 1;
    val = W1[(ct * 16 + nn) * 64 + (s * 32 + kn)];
  } else if (idx < O_R3) {         // R2, KS=8
    int g = (idx - O_R2) >> 9; int s = g & 7; int ct = g >> 3;
    val = W2[(ct * 16 + nn) * 256 + (s * 32 + kn)];
  } else if (idx < O_R4) {         // R3, KS=8
    int g = (idx - O_R3) >> 9; int s = g & 7; int ct = g >> 3;
    val = W3[(ct * 16 + nn) * 256 + (s * 32 + kn)];
  } else if (idx < O_R5) {         // R4, KS=2
    int g = (idx - O_R4) >> 9; int s = g & 1; int ct = g >> 1;
    val = W3[(s * 32 + kn) * 256 + (ct * 16 + nn)];
  } else if (idx < O_R6) {         // R5, KS=8
    int g = (idx - O_R5) >> 9; int s = g & 7; int ct = g >> 3;
    val = W2[(s * 32 + kn) * 256 + (ct * 16 + nn)];
  } else {                         // R6, KS=8
    int g = (idx - O_R6) >> 9; int s = g & 7; int ct = g >> 3;
    val = W1[(s * 32 + kn) * 64 + (ct * 16 + nn)];
  }
  wsb[idx] = f2bf(val);
}

// LDS (per block, M=32):
//  H1  32x256 bf16 swz  (16K) - h1, written G1; frags for G2; mask scalars for G5
//  H2  32x256 bf16 swz  (16K) - h2, written G2; frags for G3; mask scalars for G4/G4'
//  U2  32x256 bf16 swz  (16K) - u2, written G4/G4'; frags for G5
//  U1  32x256 bf16 swz  (16K) - u1, written G5; frags for G6
//  WB  32x64  bf16 swz  (4K)  - w,  written G6; frags for G4'
//  LDP f32[32][4]       (512B)
#define L_H2  16384
#define L_U2  32768
#define L_U1  49152
#define L_WB  65536
#define L_LDP 69632
#define L_SIZE 70144

__global__ void __launch_bounds__(512, 4)
invres_main(const float* __restrict__ y, const float* __restrict__ ldj,
            const float* __restrict__ v, const float* __restrict__ b1,
            const float* __restrict__ b2, const float* __restrict__ b3,
            const unsigned short* __restrict__ wsb, float* __restrict__ out) {
  extern __shared__ char smem[];
  char* H1 = smem;
  char* H2 = smem + L_H2;
  char* U2 = smem + L_U2;
  char* U1 = smem + L_U1;
  char* WB = smem + L_WB;
  float* ldp = (float*)(smem + L_LDP);

  const int tid = threadIdx.x;
  const int lane = tid & 63;
  const int wid = tid >> 6;          // 0..7
  const int l15 = lane & 15, g16 = lane >> 4;
  const int ct0 = wid * 2;           // wide: col tiles ct0, ct0+1 (32 cols)
  const int mh = wid >> 2;           // narrow: row half (16 rows)
  const int ctn = wid & 3;           // narrow: col tile (16 cols)
  const int r0 = blockIdx.x * 32;

  const bf16x8* R1 = (const bf16x8*)(wsb + O_R1);
  const bf16x8* R2 = (const bf16x8*)(wsb + O_R2);
  const bf16x8* R3 = (const bf16x8*)(wsb + O_R3);
  const bf16x8* R4 = (const bf16x8*)(wsb + O_R4);
  const bf16x8* R5 = (const bf16x8*)(wsb + O_R5);
  const bf16x8* R6 = (const bf16x8*)(wsb + O_R6);

  // A-fragment (16x16x32) from 32x256 swizzled LDS buffer
  auto ldsA = [&](const char* buf, int mm, int s) -> bf16x8 {
    int row = mm * 16 + l15;
    unsigned byte = ((unsigned)(s * 64 + g16 * 16)) ^ ((unsigned)(row & 7) << 4);
    return *(const bf16x8*)(buf + row * 512 + byte);
  };
  // D-layout store into 32x256 swizzled LDS buffer (wide phases)
  auto dstoreW = [&](char* buf, int mm, int cc, int r, float val) {
    int row = mm * 16 + g16 * 4 + r;
    int col = (ct0 + cc) * 16 + l15;
    *(unsigned short*)(buf + row * 512 + (((unsigned)(col * 2)) ^ ((unsigned)(row & 7) << 4))) = f2bf(val);
  };
  // ELU' mask from stored activation h: d = h>0 ? 1 : h+1
  auto maskW = [&](const char* buf, int mm, int cc, int r) -> float {
    int row = mm * 16 + g16 * 4 + r;
    int col = (ct0 + cc) * 16 + l15;
    unsigned short hv = *(const unsigned short*)(buf + row * 512 + (((unsigned)(col * 2)) ^ ((unsigned)(row & 7) << 4)));
    float h = bf2f(hv);
    return h > 0.f ? 1.f : h + 1.f;
  };
  // global A-fragment from y/v (row-major fp32), NT
  auto gA = [&](const float* p, int mm, int s, bool elu) -> bf16x8 {
    const float* q = p + (size_t)(r0 + mm * 16 + l15) * 64 + s * 32 + g16 * 8;
    f32x4 a = __builtin_nontemporal_load((const f32x4*)q);
    f32x4 b = __builtin_nontemporal_load((const f32x4*)(q + 4));
    float xv[8] = {a[0], a[1], a[2], a[3], b[0], b[1], b[2], b[3]};
    bf16x8 f;
#pragma unroll
    for (int i = 0; i < 8; i++) {
      float x = xv[i];
      if (elu) x = x > 0.f ? x : (__expf(x) - 1.f);
      f[i] = (short)f2bf(x);
    }
    return f;
  };

  float bb1[2], bb2[2];
#pragma unroll
  for (int cc = 0; cc < 2; cc++) {
    bb1[cc] = b1[(ct0 + cc) * 16 + l15];
    bb2[cc] = b2[(ct0 + cc) * 16 + l15];
  }
  const float bb3 = b3[ctn * 16 + l15];

  unsigned d0p[2], v0p[2];
  float ldacc[4] = {0.f, 0.f, 0.f, 0.f};

  // ---------------- G1: h1 = elu(elu(y) @ W1^T + b1) -> H1 ----------------
  {
    f32x4 acc[2][2] = {};
#pragma unroll
    for (int s = 0; s < 2; s++) {
      bf16x8 a0 = gA(y, 0, s, true);
      bf16x8 a1 = gA(y, 1, s, true);
#pragma unroll
      for (int cc = 0; cc < 2; cc++) {
        bf16x8 B = R1[((ct0 + cc) * 2 + s) * 64 + lane];
        acc[0][cc] = MFMA16(a0, B, acc[0][cc]);
        acc[1][cc] = MFMA16(a1, B, acc[1][cc]);
      }
    }
#pragma unroll
    for (int mm = 0; mm < 2; mm++)
#pragma unroll
      for (int cc = 0; cc < 2; cc++)
#pragma unroll
        for (int r = 0; r < 4; r++) {
          float a = acc[mm][cc][r] + bb1[cc];
          float h = a > 0.f ? a : (__expf(a) - 1.f);
          dstoreW(H1, mm, cc, r, h);
        }
  }
  __syncthreads();

  // ---------------- G2: h2 = elu(h1 @ W2^T + b2) -> H2 ----------------
  {
    f32x4 acc[2][2] = {};
#pragma unroll 1
    for (int s = 0; s < 8; s++) {
      bf16x8 a0 = ldsA(H1, 0, s);
      bf16x8 a1 = ldsA(H1, 1, s);
#pragma unroll
      for (int cc = 0; cc < 2; cc++) {
        bf16x8 B = R2[((ct0 + cc) * 8 + s) * 64 + lane];
        acc[0][cc] = MFMA16(a0, B, acc[0][cc]);
        acc[1][cc] = MFMA16(a1, B, acc[1][cc]);
      }
    }
#pragma unroll
    for (int mm = 0; mm < 2; mm++)
#pragma unroll
      for (int cc = 0; cc < 2; cc++)
#pragma unroll
        for (int r = 0; r < 4; r++) {
          float a = acc[mm][cc][r] + bb2[cc];
          float h = a > 0.f ? a : (__expf(a) - 1.f);
          dstoreW(H2, mm, cc, r, h);
        }
  }
  __syncthreads();

  // ---------------- G3: z = y + h2 @ W3^T + b3 ; d0, v0 ----------------
  {
    f32x4 acc = {};
#pragma unroll 1
    for (int s = 0; s < 8; s++)
      acc = MFMA16(ldsA(H2, mh, s), R3[(ctn * 8 + s) * 64 + lane], acc);
#pragma unroll
    for (int r = 0; r < 4; r++) {
      int row = r0 + mh * 16 + g16 * 4 + r;
      int col = ctn * 16 + l15;
      size_t off = (size_t)row * 64 + col;
      float yv = __builtin_nontemporal_load(y + off);
      __builtin_nontemporal_store(yv + acc[r] + bb3, out + off);
      unsigned dd = f2bf(yv > 0.f ? 1.f : __expf(yv));
      unsigned vv = f2bf(__builtin_nontemporal_load(v + off));
      d0p[r >> 1] = (r & 1) ? (d0p[r >> 1] | (dd << 16)) : dd;
      v0p[r >> 1] = (r & 1) ? (v0p[r >> 1] | (vv << 16)) : vv;
    }
  }

  // ---------------- G4 (k=1): u2 = (v0 @ W3) * d2 -> U2 ----------------
  {
    f32x4 acc[2][2] = {};
#pragma unroll
    for (int s = 0; s < 2; s++) {
      bf16x8 a0 = gA(v, 0, s, false);
      bf16x8 a1 = gA(v, 1, s, false);
#pragma unroll
      for (int cc = 0; cc < 2; cc++) {
        bf16x8 B = R4[((ct0 + cc) * 2 + s) * 64 + lane];
        acc[0][cc] = MFMA16(a0, B, acc[0][cc]);
        acc[1][cc] = MFMA16(a1, B, acc[1][cc]);
      }
    }
#pragma unroll
    for (int mm = 0; mm < 2; mm++)
#pragma unroll
      for (int cc = 0; cc < 2; cc++)
#pragma unroll
        for (int r = 0; r < 4; r++) {
          float u = acc[mm][cc][r] * maskW(H2, mm, cc, r);
          dstoreW(U2, mm, cc, r, u);
        }
  }
  __syncthreads();

  // ---------------- backward iterations ----------------
  for (int k = 1; k <= 8; ++k) {
    // G5: u1 = (u2 @ W2) * d1 -> U1   (d1 from H1)
    {
      f32x4 acc[2][2] = {};
#pragma unroll 1
      for (int s = 0; s < 8; s++) {
        bf16x8 a0 = ldsA(U2, 0, s);
        bf16x8 a1 = ldsA(U2, 1, s);
#pragma unroll
        for (int cc = 0; cc < 2; cc++) {
          bf16x8 B = R5[((ct0 + cc) * 8 + s) * 64 + lane];
          acc[0][cc] = MFMA16(a0, B, acc[0][cc]);
          acc[1][cc] = MFMA16(a1, B, acc[1][cc]);
        }
      }
#pragma unroll
      for (int mm = 0; mm < 2; mm++)
#pragma unroll
        for (int cc = 0; cc < 2; cc++)
#pragma unroll
          for (int r = 0; r < 4; r++) {
            float u = acc[mm][cc][r] * maskW(H1, mm, cc, r);
            dstoreW(U1, mm, cc, r, u);
          }
    }
    __syncthreads();

    // G6: w' = (u1 @ W1) * d0 ; log-det ; w' -> WB
    {
      float coef = (k & 1) ? (1.f / (float)k) : (-1.f / (float)k);
      f32x4 acc = {};
#pragma unroll 1
      for (int s = 0; s < 8; s++)
        acc = MFMA16(ldsA(U1, mh, s), R6[(ctn * 8 + s) * 64 + lane], acc);
#pragma unroll
      for (int r = 0; r < 4; r++) {
        float wv = acc[r] * bf2f((d0p[r >> 1] >> ((r & 1) * 16)) & 0xffffu);
        ldacc[r] += coef * wv * bf2f((v0p[r >> 1] >> ((r & 1) * 16)) & 0xffffu);
        if (k < 8) {
          int row = mh * 16 + g16 * 4 + r;
          int col = ctn * 16 + l15;
          *(unsigned short*)(WB + row * 128 + (((unsigned)(col * 2)) ^ ((unsigned)(row & 7) << 4))) = f2bf(wv);
        }
      }
    }
    if (k < 8) {
      __syncthreads();
      // G4': u2 = (w' @ W3) * d2 -> U2   (d2 from H2)
      f32x4 acc[2][2] = {};
#pragma unroll
      for (int s = 0; s < 2; s++) {
        bf16x8 a0, a1;
#pragma unroll
        for (int mm = 0; mm < 2; mm++) {
          int row = mm * 16 + l15;
          unsigned byte = ((unsigned)(s * 64 + g16 * 16)) ^ ((unsigned)(row & 7) << 4);
          bf16x8 a = *(const bf16x8*)(WB + row * 128 + byte);
          if (mm == 0) a0 = a; else a1 = a;
        }
#pragma unroll
        for (int cc = 0; cc < 2; cc++) {
          bf16x8 B = R4[((ct0 + cc) * 2 + s) * 64 + lane];
          acc[0][cc] = MFMA16(a0, B, acc[0][cc]);
          acc[1][cc] = MFMA16(a1, B, acc[1][cc]);
        }
      }
#pragma unroll
      for (int mm = 0; mm < 2; mm++)
#pragma unroll
        for (int cc = 0; cc < 2; cc++)
#pragma unroll
          for (int r = 0; r < 4; r++) {
            float u = acc[mm][cc][r] * maskW(H2, mm, cc, r);
            dstoreW(U2, mm, cc, r, u);
          }
      __syncthreads();
    }
  }

  // ---------------- log-det epilogue ----------------
#pragma unroll
  for (int r = 0; r < 4; r++) {
    float s = ldacc[r];
    s += __shfl_xor(s, 1);
    s += __shfl_xor(s, 2);
    s += __shfl_xor(s, 4);
    s += __shfl_xor(s, 8);
    ldacc[r] = s;
  }
  if (l15 == 0) {
#pragma unroll
    for (int r = 0; r < 4; r++) {
      int row = mh * 16 + g16 * 4 + r;
      ldp[row * 4 + ctn] = ldacc[r];
    }
  }
  __syncthreads();
  if (tid < 32) {
    float s = ldp[tid * 4] + ldp[tid * 4 + 1] + ldp[tid * 4 + 2] + ldp[tid * 4 + 3];
    int gb = r0 + tid;
    __builtin_nontemporal_store(ldj[gb] + s, out + (size_t)BN * 64 + gb);
  }
}

extern "C" void kernel_launch(void* const* d_in, const int* in_sizes, int n_in,
                              void* d_out, int out_size, void* d_ws, size_t ws_size,
                              hipStream_t stream) {
  const float* y   = (const float*)d_in[0];
  const float* ldj = (const float*)d_in[1];
  const float* v   = (const float*)d_in[2];
  const float* W1  = (const float*)d_in[3];
  const float* b1  = (const float*)d_in[4];
  const float* W2  = (const float*)d_in[5];
  const float* b2  = (const float*)d_in[6];
  const float* W3  = (const float*)d_in[7];
  const float* b3  = (const float*)d_in[8];
  unsigned short* wsb = (unsigned short*)d_ws;
  float* out = (float*)d_out;

  (void)hipFuncSetAttribute(reinterpret_cast<const void*>(&invres_main),
                            hipFuncAttributeMaxDynamicSharedMemorySize, L_SIZE);

  invres_prep<<<N_WS / 256, 256, 0, stream>>>(W1, W2, W3, wsb);
  invres_main<<<BN / 32, 512, L_SIZE, stream>>>(y, ldj, v, b1, b2, b3, wsb, out);
}

// Round 10
// 841.702 us; speedup vs baseline: 5.4044x; 1.1085x over previous
//
#include <hip/hip_runtime.h>

#define BN 262144

typedef short bf16x8 __attribute__((ext_vector_type(8)));
typedef float f32x4 __attribute__((ext_vector_type(4)));

#define MFMA16(a,b,c) __builtin_amdgcn_mfma_f32_16x16x32_bf16((a),(b),(c),0,0,0)

__device__ __forceinline__ unsigned short f2bf(float f) {
  union { float f; unsigned int u; } x; x.f = f;
  unsigned int u = x.u + 0x7fffu + ((x.u >> 16) & 1u);
  return (unsigned short)(u >> 16);
}
__device__ __forceinline__ float bf2f(unsigned int h) {
  union { unsigned int u; float f; } x; x.u = h << 16;
  return x.f;
}
// truncating f32->bf16 (1 VALU op); bias ~2^-9 rel, fine for staged intermediates
__device__ __forceinline__ unsigned short tbf(float f) {
  union { float f; unsigned int u; } x; x.f = f;
  return (unsigned short)(x.u >> 16);
}

// All weight arrays in 16x16x32 B-fragment layout (ushort units):
// elem ((ct*KS+s)*64+lane)*8+j holds B[k][n], n = ct*16+(lane&15), k = s*32+(lane>>4)*8+j
#define O_R1 0        // W1^T: B[k][n]=W1[n*64+k]   K=64  N=256 KS=2
#define O_R2 16384    // W2^T: B[k][n]=W2[n*256+k]  K=256 N=256 KS=8
#define O_R3 81920    // W3^T: B[k][n]=W3[n*256+k]  K=256 N=64  KS=8
#define O_R4 98304    // W3  : B[k][n]=W3[k*256+n]  K=64  N=256 KS=2
#define O_R5 114688   // W2  : B[k][n]=W2[k*256+n]  K=256 N=256 KS=8
#define O_R6 180224   // W1  : B[k][n]=W1[k*64+n]   K=256 N=64  KS=8
#define N_WS 196608

__global__ void invres_prep(const float* __restrict__ W1, const float* __restrict__ W2,
                            const float* __restrict__ W3, unsigned short* __restrict__ wsb) {
  int idx = blockIdx.x * 256 + threadIdx.x;
  if (idx >= N_WS) return;
  int j = idx & 7;
  int lane = (idx >> 3) & 63;
  int nn = lane & 15, kn = (lane >> 4) * 8 + j;
  float val;
  if (idx < O_R2) {                // R1, KS=2
    int g = idx >> 9; int s = g & 1; int ct = g >> 1;
    val = W1[(ct * 16 + nn) * 64 + (s * 32 + kn)];
  } else if (idx < O_R3) {         // R2, KS=8
    int g = (idx - O_R2) >> 9; int s = g & 7; int ct = g >> 3;
    val = W2[(ct * 16 + nn) * 256 + (s * 32 + kn)];
  } else if (idx < O_R4) {         // R3, KS=8
    int g = (idx - O_R3) >> 9; int s = g & 7; int ct = g >> 3;
    val = W3[(ct * 16 + nn) * 256 + (s * 32 + kn)];
  } else if (idx < O_R5) {         // R4, KS=2
    int g = (idx - O_R4) >> 9; int s = g & 1; int ct = g >> 1;
    val = W3[(s * 32 + kn) * 256 + (ct * 16 + nn)];
  } else if (idx < O_R6) {         // R5, KS=8
    int g = (idx - O_R5) >> 9; int s = g & 7; int ct = g >> 3;
    val = W2[(s * 32 + kn) * 256 + (ct * 16 + nn)];
  } else {                         // R6, KS=8
    int g = (idx - O_R6) >> 9; int s = g & 7; int ct = g >> 3;
    val = W1[(s * 32 + kn) * 64 + (ct * 16 + nn)];
  }
  wsb[idx] = f2bf(val);
}

// LDS (per block, M=32), buffers aliased across phases:
//  PA 32x256 bf16 swz (16K): h1 (G1 out, G2 in) then u2 (G4/G4' out, G5 in)
//  PB 32x256 bf16 swz (16K): h2 (G2 out, G3 in) then u1 (G5 out, G6 in)
//  WB 32x64  bf16 swz (4K) : w  (G6 out, G4' in)
//  LDP f32[32][4] (512B)
#define L_PB  16384
#define L_WB  32768
#define L_LDP 36864
#define L_SIZE 37376

__global__ void __launch_bounds__(512, 4)
invres_main(const float* __restrict__ y, const float* __restrict__ ldj,
            const float* __restrict__ v, const float* __restrict__ b1,
            const float* __restrict__ b2, const float* __restrict__ b3,
            const unsigned short* __restrict__ wsb, float* __restrict__ out) {
  extern __shared__ char smem[];
  char* PA = smem;
  char* PB = smem + L_PB;
  char* WB = smem + L_WB;
  float* ldp = (float*)(smem + L_LDP);

  const int tid = threadIdx.x;
  const int lane = tid & 63;
  const int wid = tid >> 6;          // 0..7
  const int l15 = lane & 15, g16 = lane >> 4;
  const int ct0 = wid * 2;           // wide: col tiles ct0, ct0+1 (32 cols)
  const int mh = wid >> 2;           // narrow: row half (16 rows)
  const int ctn = wid & 3;           // narrow: col tile (16 cols)
  const int r0 = blockIdx.x * 32;

  const bf16x8* R1 = (const bf16x8*)(wsb + O_R1);
  const bf16x8* R2 = (const bf16x8*)(wsb + O_R2);
  const bf16x8* R3 = (const bf16x8*)(wsb + O_R3);
  const bf16x8* R4 = (const bf16x8*)(wsb + O_R4);
  const bf16x8* R5 = (const bf16x8*)(wsb + O_R5);
  const bf16x8* R6 = (const bf16x8*)(wsb + O_R6);

  // A-fragment (16x16x32) from 32x256 swizzled LDS buffer
  auto ldsA = [&](const char* buf, int mm, int s) -> bf16x8 {
    int row = mm * 16 + l15;
    unsigned byte = ((unsigned)(s * 64 + g16 * 16)) ^ ((unsigned)(row & 7) << 4);
    return *(const bf16x8*)(buf + row * 512 + byte);
  };
  // D-layout truncating store into 32x256 swizzled LDS buffer (wide phases)
  auto dstoreW = [&](char* buf, int mm, int cc, int r, float val) {
    int row = mm * 16 + g16 * 4 + r;
    int col = (ct0 + cc) * 16 + l15;
    *(unsigned short*)(buf + row * 512 + (((unsigned)(col * 2)) ^ ((unsigned)(row & 7) << 4))) = tbf(val);
  };
  // global A-fragment from y/v (row-major fp32), NT
  auto gA = [&](const float* p, int mm, int s, bool elu) -> bf16x8 {
    const float* q = p + (size_t)(r0 + mm * 16 + l15) * 64 + s * 32 + g16 * 8;
    f32x4 a = __builtin_nontemporal_load((const f32x4*)q);
    f32x4 b = __builtin_nontemporal_load((const f32x4*)(q + 4));
    float xv[8] = {a[0], a[1], a[2], a[3], b[0], b[1], b[2], b[3]};
    bf16x8 f;
#pragma unroll
    for (int i = 0; i < 8; i++) {
      float x = xv[i];
      if (elu) x = x > 0.f ? x : (__expf(x) - 1.f);
      f[i] = (short)f2bf(x);
    }
    return f;
  };

  float bb1[2], bb2[2];
#pragma unroll
  for (int cc = 0; cc < 2; cc++) {
    bb1[cc] = b1[(ct0 + cc) * 16 + l15];
    bb2[cc] = b2[(ct0 + cc) * 16 + l15];
  }
  const float bb3 = b3[ctn * 16 + l15];

  unsigned d1p[8], d2p[8], d0p[2], v0p[2];
  float ldacc[4] = {0.f, 0.f, 0.f, 0.f};

  // ---------------- G1: h1 = elu(elu(y) @ W1^T + b1) -> PA ; d1 -> regs ----------------
  {
    f32x4 acc[2][2] = {};
#pragma unroll
    for (int s = 0; s < 2; s++) {
      bf16x8 a0 = gA(y, 0, s, true);
      bf16x8 a1 = gA(y, 1, s, true);
#pragma unroll
      for (int cc = 0; cc < 2; cc++) {
        bf16x8 B = R1[((ct0 + cc) * 2 + s) * 64 + lane];
        acc[0][cc] = MFMA16(a0, B, acc[0][cc]);
        acc[1][cc] = MFMA16(a1, B, acc[1][cc]);
      }
    }
#pragma unroll
    for (int mm = 0; mm < 2; mm++)
#pragma unroll
      for (int cc = 0; cc < 2; cc++)
#pragma unroll
        for (int r = 0; r < 4; r++) {
          float a = acc[mm][cc][r] + bb1[cc];
          float e = __expf(a);
          float h = a > 0.f ? a : (e - 1.f);
          unsigned dd = f2bf(a > 0.f ? 1.f : e);
          dstoreW(PA, mm, cc, r, h);
          int idx = (mm * 2 + cc) * 2 + (r >> 1);
          d1p[idx] = (r & 1) ? (d1p[idx] | (dd << 16)) : dd;
        }
  }
  __syncthreads();

  // ---------------- G2: h2 = elu(h1 @ W2^T + b2) -> PB ; d2 -> regs ----------------
  {
    f32x4 acc[2][2] = {};
#pragma unroll 1
    for (int s = 0; s < 8; s++) {
      bf16x8 a0 = ldsA(PA, 0, s);
      bf16x8 a1 = ldsA(PA, 1, s);
#pragma unroll
      for (int cc = 0; cc < 2; cc++) {
        bf16x8 B = R2[((ct0 + cc) * 8 + s) * 64 + lane];
        acc[0][cc] = MFMA16(a0, B, acc[0][cc]);
        acc[1][cc] = MFMA16(a1, B, acc[1][cc]);
      }
    }
#pragma unroll
    for (int mm = 0; mm < 2; mm++)
#pragma unroll
      for (int cc = 0; cc < 2; cc++)
#pragma unroll
        for (int r = 0; r < 4; r++) {
          float a = acc[mm][cc][r] + bb2[cc];
          float e = __expf(a);
          float h = a > 0.f ? a : (e - 1.f);
          unsigned dd = f2bf(a > 0.f ? 1.f : e);
          dstoreW(PB, mm, cc, r, h);
          int idx = (mm * 2 + cc) * 2 + (r >> 1);
          d2p[idx] = (r & 1) ? (d2p[idx] | (dd << 16)) : dd;
        }
  }
  __syncthreads();

  // ---------------- G3: z = y + h2 @ W3^T + b3 ; d0, v0 ----------------
  {
    f32x4 acc = {};
#pragma unroll 1
    for (int s = 0; s < 8; s++)
      acc = MFMA16(ldsA(PB, mh, s), R3[(ctn * 8 + s) * 64 + lane], acc);
#pragma unroll
    for (int r = 0; r < 4; r++) {
      int row = r0 + mh * 16 + g16 * 4 + r;
      int col = ctn * 16 + l15;
      size_t off = (size_t)row * 64 + col;
      float yv = __builtin_nontemporal_load(y + off);
      __builtin_nontemporal_store(yv + acc[r] + bb3, out + off);
      unsigned dd = f2bf(yv > 0.f ? 1.f : __expf(yv));
      unsigned vv = f2bf(__builtin_nontemporal_load(v + off));
      d0p[r >> 1] = (r & 1) ? (d0p[r >> 1] | (dd << 16)) : dd;
      v0p[r >> 1] = (r & 1) ? (v0p[r >> 1] | (vv << 16)) : vv;
    }
  }

  // ---------------- G4 (k=1): u2 = (v0 @ W3) * d2 -> PA ----------------
  {
    f32x4 acc[2][2] = {};
#pragma unroll
    for (int s = 0; s < 2; s++) {
      bf16x8 a0 = gA(v, 0, s, false);
      bf16x8 a1 = gA(v, 1, s, false);
#pragma unroll
      for (int cc = 0; cc < 2; cc++) {
        bf16x8 B = R4[((ct0 + cc) * 2 + s) * 64 + lane];
        acc[0][cc] = MFMA16(a0, B, acc[0][cc]);
        acc[1][cc] = MFMA16(a1, B, acc[1][cc]);
      }
    }
#pragma unroll
    for (int mm = 0; mm < 2; mm++)
#pragma unroll
      for (int cc = 0; cc < 2; cc++)
#pragma unroll
        for (int r = 0; r < 4; r++) {
          int idx = (mm * 2 + cc) * 2 + (r >> 1);
          float u = acc[mm][cc][r] * bf2f((d2p[idx] >> ((r & 1) * 16)) & 0xffffu);
          dstoreW(PA, mm, cc, r, u);
        }
  }
  __syncthreads();

  // ---------------- backward iterations ----------------
  for (int k = 1; k <= 8; ++k) {
    // G5: u1 = (u2 @ W2) * d1 -> PB
    {
      f32x4 acc[2][2] = {};
#pragma unroll 1
      for (int s = 0; s < 8; s++) {
        bf16x8 a0 = ldsA(PA, 0, s);
        bf16x8 a1 = ldsA(PA, 1, s);
#pragma unroll
        for (int cc = 0; cc < 2; cc++) {
          bf16x8 B = R5[((ct0 + cc) * 8 + s) * 64 + lane];
          acc[0][cc] = MFMA16(a0, B, acc[0][cc]);
          acc[1][cc] = MFMA16(a1, B, acc[1][cc]);
        }
      }
#pragma unroll
      for (int mm = 0; mm < 2; mm++)
#pragma unroll
        for (int cc = 0; cc < 2; cc++)
#pragma unroll
          for (int r = 0; r < 4; r++) {
            int idx = (mm * 2 + cc) * 2 + (r >> 1);
            float u = acc[mm][cc][r] * bf2f((d1p[idx] >> ((r & 1) * 16)) & 0xffffu);
            dstoreW(PB, mm, cc, r, u);
          }
    }
    __syncthreads();

    // G6: w' = (u1 @ W1) * d0 ; log-det ; w' -> WB
    {
      float coef = (k & 1) ? (1.f / (float)k) : (-1.f / (float)k);
      f32x4 acc = {};
#pragma unroll 1
      for (int s = 0; s < 8; s++)
        acc = MFMA16(ldsA(PB, mh, s), R6[(ctn * 8 + s) * 64 + lane], acc);
#pragma unroll
      for (int r = 0; r < 4; r++) {
        float wv = acc[r] * bf2f((d0p[r >> 1] >> ((r & 1) * 16)) & 0xffffu);
        ldacc[r] += coef * wv * bf2f((v0p[r >> 1] >> ((r & 1) * 16)) & 0xffffu);
        if (k < 8) {
          int row = mh * 16 + g16 * 4 + r;
          int col = ctn * 16 + l15;
          *(unsigned short*)(WB + row * 128 + (((unsigned)(col * 2)) ^ ((unsigned)(row & 7) << 4))) = tbf(wv);
        }
      }
    }
    if (k < 8) {
      __syncthreads();
      // G4': u2 = (w' @ W3) * d2 -> PA
      f32x4 acc[2][2] = {};
#pragma unroll
      for (int s = 0; s < 2; s++) {
        bf16x8 a0, a1;
#pragma unroll
        for (int mm = 0; mm < 2; mm++) {
          int row = mm * 16 + l15;
          unsigned byte = ((unsigned)(s * 64 + g16 * 16)) ^ ((unsigned)(row & 7) << 4);
          bf16x8 a = *(const bf16x8*)(WB + row * 128 + byte);
          if (mm == 0) a0 = a; else a1 = a;
        }
#pragma unroll
        for (int cc = 0; cc < 2; cc++) {
          bf16x8 B = R4[((ct0 + cc) * 2 + s) * 64 + lane];
          acc[0][cc] = MFMA16(a0, B, acc[0][cc]);
          acc[1][cc] = MFMA16(a1, B, acc[1][cc]);
        }
      }
#pragma unroll
      for (int mm = 0; mm < 2; mm++)
#pragma unroll
        for (int cc = 0; cc < 2; cc++)
#pragma unroll
          for (int r = 0; r < 4; r++) {
            int idx = (mm * 2 + cc) * 2 + (r >> 1);
            float u = acc[mm][cc][r] * bf2f((d2p[idx] >> ((r & 1) * 16)) & 0xffffu);
            dstoreW(PA, mm, cc, r, u);
          }
      __syncthreads();
    }
  }

  // ---------------- log-det epilogue ----------------
#pragma unroll
  for (int r = 0; r < 4; r++) {
    float s = ldacc[r];
    s += __shfl_xor(s, 1);
    s += __shfl_xor(s, 2);
    s += __shfl_xor(s, 4);
    s += __shfl_xor(s, 8);
    ldacc[r] = s;
  }
  if (l15 == 0) {
#pragma unroll
    for (int r = 0; r < 4; r++) {
      int row = mh * 16 + g16 * 4 + r;
      ldp[row * 4 + ctn] = ldacc[r];
    }
  }
  __syncthreads();
  if (tid < 32) {
    float s = ldp[tid * 4] + ldp[tid * 4 + 1] + ldp[tid * 4 + 2] + ldp[tid * 4 + 3];
    int gb = r0 + tid;
    __builtin_nontemporal_store(ldj[gb] + s, out + (size_t)BN * 64 + gb);
  }
}

extern "C" void kernel_launch(void* const* d_in, const int* in_sizes, int n_in,
                              void* d_out, int out_size, void* d_ws, size_t ws_size,
                              hipStream_t stream) {
  const float* y   = (const float*)d_in[0];
  const float* ldj = (const float*)d_in[1];
  const float* v   = (const float*)d_in[2];
  const float* W1  = (const float*)d_in[3];
  const float* b1  = (const float*)d_in[4];
  const float* W2  = (const float*)d_in[5];
  const float* b2  = (const float*)d_in[6];
  const float* W3  = (const float*)d_in[7];
  const float* b3  = (const float*)d_in[8];
  unsigned short* wsb = (unsigned short*)d_ws;
  float* out = (float*)d_out;

  (void)hipFuncSetAttribute(reinterpret_cast<const void*>(&invres_main),
                            hipFuncAttributeMaxDynamicSharedMemorySize, L_SIZE);

  invres_prep<<<N_WS / 256, 256, 0, stream>>>(W1, W2, W3, wsb);
  invres_main<<<BN / 32, 512, L_SIZE, stream>>>(y, ldj, v, b1, b2, b3, wsb, out);
}